// Round 17
// baseline (89.247 us; speedup 1.0000x reference)
//
#include <hip/hip_runtime.h>
#include <hip/hip_bf16.h>
#include <math.h>

#define NN 8192
#define INF_ 128
#define OUTF 64

typedef __attribute__((ext_vector_type(4))) float f32x4;
typedef __attribute__((ext_vector_type(4))) int i32x4;
typedef __attribute__((ext_vector_type(8))) unsigned short u16x8;
typedef __attribute__((ext_vector_type(8))) __bf16 bf16x8;

// barrier WITHOUT vmcnt drain: LDS visibility only (lgkmcnt).
#define BAR()                                                    \
    {                                                            \
        asm volatile("s_waitcnt lgkmcnt(0)" ::: "memory");       \
        __builtin_amdgcn_s_barrier();                            \
    }

__device__ __forceinline__ unsigned short f2bf(float f) {
    unsigned int u = __float_as_uint(f);
    u = (u + 0x7FFFu + ((u >> 16) & 1u)) >> 16;
    return (unsigned short)u;
}

// ---- Kernel 1: Wh = h@W (fp32); f1 = Wh@a1; f2 = Wh@a2; WhT = bf16(Wh)^T [64][8192]
__global__ __launch_bounds__(256) void prep_kernel(
    const float* __restrict__ h, const float* __restrict__ W,
    const float* __restrict__ a, unsigned short* __restrict__ WhT,
    float* __restrict__ f1, float* __restrict__ f2)
{
    __shared__ float W_lds[INF_ * OUTF];
    __shared__ float h_lds[32 * INF_];
    __shared__ unsigned short t_lds[OUTF * 34];

    const int t = threadIdx.x;
    const int rb = blockIdx.x * 32;

    {
        const float4* Ws = (const float4*)W;
        float4* Wd = (float4*)W_lds;
        #pragma unroll
        for (int q = 0; q < 8; ++q) Wd[t + 256 * q] = Ws[t + 256 * q];
        const float4* hs = (const float4*)(h + (size_t)rb * INF_);
        float4* hd = (float4*)h_lds;
        #pragma unroll
        for (int q = 0; q < 4; ++q) hd[t + 256 * q] = hs[t + 256 * q];
    }
    __syncthreads();

    const int lane = t & 63;
    const int w = t >> 6;

    float acc[8];
    #pragma unroll
    for (int q = 0; q < 8; ++q) acc[q] = 0.f;
    for (int k = 0; k < INF_; ++k) {
        const float wv = W_lds[k * OUTF + lane];
        #pragma unroll
        for (int q = 0; q < 8; ++q)
            acc[q] = fmaf(h_lds[(w * 8 + q) * INF_ + k], wv, acc[q]);
    }

    const float a1 = a[lane];
    const float a2 = a[OUTF + lane];
    #pragma unroll
    for (int q = 0; q < 8; ++q) {
        float s1 = acc[q] * a1;
        float s2 = acc[q] * a2;
        #pragma unroll
        for (int m = 1; m < 64; m <<= 1) {
            s1 += __shfl_xor(s1, m, 64);
            s2 += __shfl_xor(s2, m, 64);
        }
        if (lane == 0) {
            f1[rb + w * 8 + q] = s1;
            f2[rb + w * 8 + q] = s2;
        }
        t_lds[lane * 34 + w * 8 + q] = f2bf(acc[q]);
    }
    __syncthreads();
    {
        const int c = t >> 2;
        const int ro = (t & 3) * 8;
        unsigned int pk[4];
        #pragma unroll
        for (int i = 0; i < 4; ++i) {
            const unsigned int lo = t_lds[c * 34 + ro + 2 * i];
            const unsigned int hi = t_lds[c * 34 + ro + 2 * i + 1];
            pk[i] = lo | (hi << 16);
        }
        *(uint4*)(WhT + (size_t)c * NN + rb + ro) = make_uint4(pk[0], pk[1], pk[2], pk[3]);
    }
}

// ---- Kernel 1b: f2max = max_j f2[j]
__global__ __launch_bounds__(1024) void fmax_kernel(
    const float* __restrict__ f2, float* __restrict__ f2max)
{
    __shared__ float red[16];
    const int t = threadIdx.x;
    float m = -INFINITY;
    #pragma unroll
    for (int q = 0; q < NN / 1024; ++q) m = fmaxf(m, f2[t + q * 1024]);
    #pragma unroll
    for (int s = 1; s < 64; s <<= 1) m = fmaxf(m, __shfl_xor(m, s, 64));
    if ((t & 63) == 0) red[t >> 6] = m;
    __syncthreads();
    if (t == 0) {
        float r = red[0];
        #pragma unroll
        for (int i = 1; i < 16; ++i) r = fmaxf(r, red[i]);
        f2max[0] = r;
    }
}

// ---- Kernel 1c: repack WhT into lane-contiguous B-fragments.
__global__ __launch_bounds__(256) void repack_kernel(
    const unsigned short* __restrict__ WhT, unsigned short* __restrict__ WhTs)
{
    const int ch = blockIdx.x;    // 256 chunks of 32 j
    const int t = threadIdx.x;
    const int qd = t >> 6, l = t & 63;
    const int r = l & 15, g = l >> 4;
    const u16x8 v = *(const u16x8*)(WhT + (size_t)(qd * 16 + r) * NN + ch * 32 + g * 8);
    *(u16x8*)(WhTs + (size_t)ch * 2048 + qd * 512 + l * 8) = v;
}

// ---- Kernel 1d: bd[j] = pack(bf16(exp(f2_j)), bf16(exp(0.2*f2_j)))
__global__ __launch_bounds__(1024) void bd_kernel(
    const float* __restrict__ f2, unsigned int* __restrict__ bd)
{
    const int i = blockIdx.x * 1024 + threadIdx.x;
    const float v = f2[i];
    const unsigned int B = f2bf(expf(v));
    const unsigned int D = f2bf(expf(0.2f * v));
    bd[i] = B | (D << 16);
}

// ---- Kernel 2: per-wave two-phase (NO barriers between phases across waves).
// Phase A: stream 16 rows x 1024 j of adj (i32x4 lane-contiguous), ballot,
//          keep ALL mask bits in registers km[4][4] (32 VGPRs).
// Phase B: pure consume - the ONLY VMEM is the wq L2 stream (depth-2
//          pipelined); masks from registers, bd from LDS.
// Waves on a CU de-phase naturally: A (HBM) overlaps other waves' B (compute).
__global__ __launch_bounds__(512) void gatw_kernel(
    const int* __restrict__ adj, const unsigned short* __restrict__ WhTs,
    const float* __restrict__ f1, const unsigned int* __restrict__ bd,
    const float* __restrict__ f2max, float* __restrict__ out)
{
    __shared__ float acc_lds[8 * 16 * OUTF];  // 32 KB partials
    __shared__ unsigned int bd_lds[NN];       // 32 KB (B,D) bf16 pairs
    __shared__ float l_lds[8 * 16];

    const int t = threadIdx.x;
    const int lane = t & 63;
    const int w = t >> 6;
    const int r = lane & 15;     // A-frag row / D feature
    const int g = lane >> 4;     // k-group
    const int row_base = blockIdx.x * 16;

    // stage bd (32 KB) cooperatively (loads retire before phase A's adj)
    #pragma unroll
    for (int q = 0; q < 4; ++q)
        ((uint4*)bd_lds)[t + 512 * q] = ((const uint4*)bd)[t + 512 * q];

    // ======== phase A: adj stream -> in-register masks ========
    // ballot(v[c]) bit l <-> j = q*256 + 4*l + c  (r3/r15-verified mapping)
    const int j0 = w * 1024;
    const int* base = adj + (size_t)row_base * NN + j0 + 4 * lane;
    unsigned long long km[4][4];
    {
        i32x4 st[16];
        #pragma unroll
        for (int rr = 0; rr < 16; ++rr)
            st[rr] = *(const i32x4*)(base + (size_t)rr * NN);

        #pragma unroll
        for (int q = 0; q < 4; ++q) {
            #pragma unroll
            for (int rr = 0; rr < 16; ++rr) {
                const i32x4 v = st[rr];
                const unsigned long long b0 = __ballot(v[0] > 0);
                const unsigned long long b1 = __ballot(v[1] > 0);
                const unsigned long long b2 = __ballot(v[2] > 0);
                const unsigned long long b3 = __ballot(v[3] > 0);
                if (rr == r) {
                    km[q][0] = b0; km[q][1] = b1; km[q][2] = b2; km[q][3] = b3;
                }
            }
            if (q + 1 < 4) {
                #pragma unroll
                for (int rr = 0; rr < 16; ++rr)
                    st[rr] = *(const i32x4*)(base + (size_t)rr * NN + (q + 1) * 256);
            }
        }
    }

    // ======== phase B setup ========
    const float f1r = f1[row_base + r];
    float Mr = f1r + f2max[0];
    Mr = fmaxf(Mr, 0.2f * Mr);
    const float A = expf(f1r - Mr);          // e>0 branch row factor
    const float C = expf(0.2f * f1r - Mr);   // e<=0 branch row factor
    const unsigned int THb = (unsigned int)f2bf(expf(-f1r)); // B_j > THb <=> e>0

    f32x4 accl = {0.f, 0.f, 0.f, 0.f};
    f32x4 acc[4];
    #pragma unroll
    for (int q = 0; q < 4; ++q) acc[q] = accl;

    u16x8 ones_u;
    #pragma unroll
    for (int i = 0; i < 8; ++i) ones_u[i] = 0x3F80;
    const bf16x8 bones = __builtin_bit_cast(bf16x8, ones_u);

    BAR(); // bd_lds visible to all waves; adj fully consumed (A done)

    // ======== phase B: consume 32 chunks; VMEM = wq only, depth-2 ========
    {
        const u16x8* wv = (const u16x8*)WhTs + lane; // + (ch*4+qd)*64
        const int chb = w * 32;

        u16x8 wq0[4], wq1[4];
        #pragma unroll
        for (int qd = 0; qd < 4; ++qd)
            wq0[qd] = wv[((size_t)chb * 4 + qd) * 64];

        #pragma unroll
        for (int ci = 0; ci < 32; ++ci) {
            u16x8* cur = (ci & 1) ? wq1 : wq0;
            u16x8* nxt = (ci & 1) ? wq0 : wq1;
            if (ci + 1 < 32) {
                #pragma unroll
                for (int qd = 0; qd < 4; ++qd)
                    nxt[qd] = wv[((size_t)(chb + ci + 1) * 4 + qd) * 64];
            }
            const int q = ci >> 3, cq = ci & 7;
            const int ch = chb + ci;
            const int col = ch * 32 + g * 8;
            const unsigned int shq = 8 * cq + 2 * g;
            const unsigned int e0 = (unsigned int)(km[q][0] >> shq) & 3u;
            const unsigned int e1 = (unsigned int)(km[q][1] >> shq) & 3u;
            const unsigned int e2 = (unsigned int)(km[q][2] >> shq) & 3u;
            const unsigned int e3 = (unsigned int)(km[q][3] >> shq) & 3u;
            const unsigned int eb[4] = {e0, e1, e2, e3};

            const uint4 bq0 = *(const uint4*)(bd_lds + col);
            const uint4 bq1 = *(const uint4*)(bd_lds + col + 4);
            const unsigned int bdv[8] = {bq0.x, bq0.y, bq0.z, bq0.w,
                                         bq1.x, bq1.y, bq1.z, bq1.w};

            u16x8 pb;
            #pragma unroll
            for (int i = 0; i < 8; ++i) {
                const unsigned int v = bdv[i];
                const unsigned int bb = v & 0xFFFFu;
                const bool up = bb > THb;                    // e > 0 ?
                const unsigned int sel = up ? bb : (v >> 16);
                const float f = __uint_as_float(sel << 16);  // bf16 -> f32
                const float as = up ? A : C;
                const unsigned int bit = (eb[i & 3] >> (i >> 2)) & 1u;
                const float p = bit ? f * as : 0.f;
                pb[i] = __builtin_bit_cast(unsigned short, __float2bfloat16(p));
            }

            const bf16x8 af = __builtin_bit_cast(bf16x8, pb);
            #pragma unroll
            for (int qd = 0; qd < 4; ++qd) {
                const bf16x8 bq = __builtin_bit_cast(bf16x8, cur[qd]);
                acc[qd] = __builtin_amdgcn_mfma_f32_16x16x32_bf16(af, bq, acc[qd], 0, 0, 0);
            }
            accl = __builtin_amdgcn_mfma_f32_16x16x32_bf16(af, bones, accl, 0, 0, 0);
        }
    }

    // D layout: col = lane&15 (feature), row = 4*g + q
    if (r == 0) {
        #pragma unroll
        for (int q = 0; q < 4; ++q) l_lds[w * 16 + 4 * g + q] = accl[q];
    }
    #pragma unroll
    for (int q = 0; q < 4; ++q) {
        const int m = 4 * g + q;
        #pragma unroll
        for (int qd = 0; qd < 4; ++qd)
            acc_lds[(w * 16 + m) * OUTF + qd * 16 + r] = acc[qd][q];
    }
    __syncthreads();

    // merge partials across the 8 waves: 1024 outputs, 2 per thread
    {
        #pragma unroll
        for (int hh = 0; hh < 2; ++hh) {
            const int idx = t + hh * 512;
            const int row = idx >> 6;
            const int col = idx & 63;
            float L = 0.f, o = 0.f;
            #pragma unroll
            for (int ww = 0; ww < 8; ++ww) {
                L += l_lds[ww * 16 + row];
                o += acc_lds[(ww * 16 + row) * OUTF + col];
            }
            o /= L;
            o = (o > 0.f) ? o : expm1f(o); // ELU
            out[(size_t)(row_base + row) * OUTF + col] = o;
        }
    }
}

extern "C" void kernel_launch(void* const* d_in, const int* in_sizes, int n_in,
                              void* d_out, int out_size, void* d_ws, size_t ws_size,
                              hipStream_t stream) {
    const float* h = (const float*)d_in[0];
    const int* adj = (const int*)d_in[1];
    const float* W = (const float*)d_in[2];
    const float* a = (const float*)d_in[3];
    float* out = (float*)d_out;

    char* ws = (char*)d_ws;
    unsigned short* WhT = (unsigned short*)ws;                 // 1 MB
    unsigned short* WhTs = (unsigned short*)(ws + (1 << 20));  // 1 MB swizzled
    float* f1 = (float*)(ws + (2 << 20));                      // 32 KB
    float* f2 = f1 + NN;                                       // 32 KB
    float* f2m = f2 + NN;                                      // 4 B
    unsigned int* bd = (unsigned int*)(f2m + 64);              // 32 KB

    prep_kernel<<<NN / 32, 256, 0, stream>>>(h, W, a, WhT, f1, f2);
    fmax_kernel<<<1, 1024, 0, stream>>>(f2, f2m);
    bd_kernel<<<NN / 1024, 1024, 0, stream>>>(f2, bd);
    repack_kernel<<<NN / 32, 256, 0, stream>>>(WhT, WhTs);
    gatw_kernel<<<NN / 16, 512, 0, stream>>>(adj, WhTs, f1, bd, f2m, out);
}

// Round 19
// 88.137 us; speedup vs baseline: 1.0126x; 1.0126x over previous
//
#include <hip/hip_runtime.h>
#include <hip/hip_bf16.h>
#include <math.h>

#define NN 8192
#define INF_ 128
#define OUTF 64
#define RB 128      // rows per block
#define JB 512      // j per block (16 chunks x 4 KB = 64 KB LDS exactly)

typedef __attribute__((ext_vector_type(4))) float f32x4;
typedef __attribute__((ext_vector_type(4))) int i32x4;
typedef __attribute__((ext_vector_type(8))) unsigned short u16x8;
typedef __attribute__((ext_vector_type(8))) __bf16 bf16x8;

// barrier WITHOUT vmcnt drain: LDS visibility only (lgkmcnt).
#define BAR()                                                    \
    {                                                            \
        asm volatile("s_waitcnt lgkmcnt(0)" ::: "memory");       \
        __builtin_amdgcn_s_barrier();                            \
    }

__device__ __forceinline__ unsigned short f2bf(float f) {
    unsigned int u = __float_as_uint(f);
    u = (u + 0x7FFFu + ((u >> 16) & 1u)) >> 16;
    return (unsigned short)u;
}

// ---- Kernel 1: Wh = h@W (fp32); f1 = Wh@a1; f2 = Wh@a2; WhT = bf16(Wh)^T [64][8192]
__global__ __launch_bounds__(256) void prep_kernel(
    const float* __restrict__ h, const float* __restrict__ W,
    const float* __restrict__ a, unsigned short* __restrict__ WhT,
    float* __restrict__ f1, float* __restrict__ f2)
{
    __shared__ float W_lds[INF_ * OUTF];
    __shared__ float h_lds[32 * INF_];
    __shared__ unsigned short t_lds[OUTF * 34];

    const int t = threadIdx.x;
    const int rb = blockIdx.x * 32;

    {
        const float4* Ws = (const float4*)W;
        float4* Wd = (float4*)W_lds;
        #pragma unroll
        for (int q = 0; q < 8; ++q) Wd[t + 256 * q] = Ws[t + 256 * q];
        const float4* hs = (const float4*)(h + (size_t)rb * INF_);
        float4* hd = (float4*)h_lds;
        #pragma unroll
        for (int q = 0; q < 4; ++q) hd[t + 256 * q] = hs[t + 256 * q];
    }
    __syncthreads();

    const int lane = t & 63;
    const int w = t >> 6;

    float acc[8];
    #pragma unroll
    for (int q = 0; q < 8; ++q) acc[q] = 0.f;
    for (int k = 0; k < INF_; ++k) {
        const float wv = W_lds[k * OUTF + lane];
        #pragma unroll
        for (int q = 0; q < 8; ++q)
            acc[q] = fmaf(h_lds[(w * 8 + q) * INF_ + k], wv, acc[q]);
    }

    const float a1 = a[lane];
    const float a2 = a[OUTF + lane];
    #pragma unroll
    for (int q = 0; q < 8; ++q) {
        float s1 = acc[q] * a1;
        float s2 = acc[q] * a2;
        #pragma unroll
        for (int m = 1; m < 64; m <<= 1) {
            s1 += __shfl_xor(s1, m, 64);
            s2 += __shfl_xor(s2, m, 64);
        }
        if (lane == 0) {
            f1[rb + w * 8 + q] = s1;
            f2[rb + w * 8 + q] = s2;
        }
        t_lds[lane * 34 + w * 8 + q] = f2bf(acc[q]);
    }
    __syncthreads();
    {
        const int c = t >> 2;
        const int ro = (t & 3) * 8;
        unsigned int pk[4];
        #pragma unroll
        for (int i = 0; i < 4; ++i) {
            const unsigned int lo = t_lds[c * 34 + ro + 2 * i];
            const unsigned int hi = t_lds[c * 34 + ro + 2 * i + 1];
            pk[i] = lo | (hi << 16);
        }
        *(uint4*)(WhT + (size_t)c * NN + rb + ro) = make_uint4(pk[0], pk[1], pk[2], pk[3]);
    }
}

// ---- Kernel 1b: f2max = max_j f2[j]
__global__ __launch_bounds__(1024) void fmax_kernel(
    const float* __restrict__ f2, float* __restrict__ f2max)
{
    __shared__ float red[16];
    const int t = threadIdx.x;
    float m = -INFINITY;
    #pragma unroll
    for (int q = 0; q < NN / 1024; ++q) m = fmaxf(m, f2[t + q * 1024]);
    #pragma unroll
    for (int s = 1; s < 64; s <<= 1) m = fmaxf(m, __shfl_xor(m, s, 64));
    if ((t & 63) == 0) red[t >> 6] = m;
    __syncthreads();
    if (t == 0) {
        float r = red[0];
        #pragma unroll
        for (int i = 1; i < 16; ++i) r = fmaxf(r, red[i]);
        f2max[0] = r;
    }
}

// ---- Kernel 1c: repack WhT into lane-contiguous B-fragments.
// chunk ch (32 j): 2048 u16 = 4 KB; within: qd*512 + lane*8 u16.
__global__ __launch_bounds__(256) void repack_kernel(
    const unsigned short* __restrict__ WhT, unsigned short* __restrict__ WhTs)
{
    const int ch = blockIdx.x;    // 256 chunks of 32 j
    const int t = threadIdx.x;
    const int qd = t >> 6, l = t & 63;
    const int r = l & 15, g = l >> 4;
    const u16x8 v = *(const u16x8*)(WhT + (size_t)(qd * 16 + r) * NN + ch * 32 + g * 8);
    *(u16x8*)(WhTs + (size_t)ch * 2048 + qd * 512 + l * 8) = v;
}

// ---- Kernel 1d: bd[j] = pack(bf16(exp(f2_j)), bf16(exp(0.2*f2_j)))
__global__ __launch_bounds__(1024) void bd_kernel(
    const float* __restrict__ f2, unsigned int* __restrict__ bd)
{
    const int i = blockIdx.x * 1024 + threadIdx.x;
    const float v = f2[i];
    const unsigned int B = f2bf(expf(v));
    const unsigned int D = f2bf(expf(0.2f * v));
    bd[i] = B | (D << 16);
}

// ---- Kernel 2: 128 rows x 512 j blocks. B-fragments (64 KB) + bd (2 KB) in
//      LDS -> consume phase has ZERO VMEM; adj stream is the only VMEM in the
//      loop. sched_barrier pins the prefetch (compiler sinks it otherwise).
__global__ __launch_bounds__(512) void gatl_kernel(
    const int* __restrict__ adj, const unsigned short* __restrict__ WhTs,
    const float* __restrict__ f1, const unsigned int* __restrict__ bd,
    const float* __restrict__ f2max, float* __restrict__ pacc,
    float* __restrict__ pl)
{
    __shared__ uint4 whts_lds[4096];       // 64 KB: 16 chunks x 256 uint4
    __shared__ unsigned int bd_lds[JB];    // 2 KB

    const int t = threadIdx.x;
    const int lane = t & 63;
    const int w = t >> 6;
    const int r = lane & 15;     // A-frag row / D feature
    const int g = lane >> 4;     // k-group
    const int rb = (blockIdx.x >> 4) * RB;
    const int jbi = blockIdx.x & 15;
    const int jb = jbi * JB;

    // issue adj segment 0 FIRST (flies during staging)
    const int* base = adj + (size_t)(rb + w * 16) * NN + jb + 4 * lane;
    i32x4 st[16];
    #pragma unroll
    for (int rr = 0; rr < 16; ++rr)
        st[rr] = *(const i32x4*)(base + (size_t)rr * NN);

    // stage this block's WhTs j-slice (64 KB) + bd slice (2 KB)
    {
        const uint4* src = (const uint4*)WhTs + (size_t)(jb >> 5) * 256;
        #pragma unroll
        for (int q = 0; q < 8; ++q) whts_lds[t + 512 * q] = src[t + 512 * q];
        if (t < 128) ((uint4*)bd_lds)[t] = ((const uint4*)(bd + jb))[t];
    }

    const float f1r = f1[rb + w * 16 + r];
    float Mr = f1r + f2max[0];
    Mr = fmaxf(Mr, 0.2f * Mr);
    const float A = expf(f1r - Mr);
    const float C = expf(0.2f * f1r - Mr);
    const unsigned int THb = (unsigned int)f2bf(expf(-f1r)); // B_j > THb <=> e>0

    f32x4 accl = {0.f, 0.f, 0.f, 0.f};
    f32x4 acc[4];
    #pragma unroll
    for (int q = 0; q < 4; ++q) acc[q] = accl;

    u16x8 ones_u;
    #pragma unroll
    for (int i = 0; i < 8; ++i) ones_u[i] = 0x3F80;
    const bf16x8 bones = __builtin_bit_cast(bf16x8, ones_u);

    BAR(); // LDS staged; adj loads still in flight

    #pragma unroll
    for (int s = 0; s < 2; ++s) {
        // ballot: lane keeps row r's 4 x u64 for this 256-j segment
        // ballot(v[c]) bit l <-> j_local = s*256 + 4*l + c  (r15/r17-verified)
        unsigned long long km[4];
        #pragma unroll
        for (int rr = 0; rr < 16; ++rr) {
            const i32x4 v = st[rr];
            const unsigned long long b0 = __ballot(v[0] > 0);
            const unsigned long long b1 = __ballot(v[1] > 0);
            const unsigned long long b2 = __ballot(v[2] > 0);
            const unsigned long long b3 = __ballot(v[3] > 0);
            if (rr == r) { km[0] = b0; km[1] = b1; km[2] = b2; km[3] = b3; }
        }
        // issue next segment's adj loads; sched_barrier pins them HERE
        if (s + 1 < 2) {
            #pragma unroll
            for (int rr = 0; rr < 16; ++rr)
                st[rr] = *(const i32x4*)(base + (size_t)rr * NN + 256);
        }
        __builtin_amdgcn_sched_barrier(0x38F); // VMEM may not cross

        // consume 8 chunks of 32 j — LDS only (whts_lds, bd_lds)
        #pragma unroll
        for (int cq = 0; cq < 8; ++cq) {
            const int chl = s * 8 + cq;           // chunk within block (0..15)
            const int coll = chl * 32 + g * 8;    // j_local of first elem
            const unsigned int shq = 8 * cq + 2 * g;
            const unsigned int e0 = (unsigned int)(km[0] >> shq) & 3u;
            const unsigned int e1 = (unsigned int)(km[1] >> shq) & 3u;
            const unsigned int e2 = (unsigned int)(km[2] >> shq) & 3u;
            const unsigned int e3 = (unsigned int)(km[3] >> shq) & 3u;
            const unsigned int eb[4] = {e0, e1, e2, e3};

            const uint4 bq0 = *(const uint4*)(bd_lds + coll);
            const uint4 bq1 = *(const uint4*)(bd_lds + coll + 4);
            const unsigned int bdv[8] = {bq0.x, bq0.y, bq0.z, bq0.w,
                                         bq1.x, bq1.y, bq1.z, bq1.w};

            u16x8 pb;
            #pragma unroll
            for (int i = 0; i < 8; ++i) {
                const unsigned int v = bdv[i];
                const unsigned int bb = v & 0xFFFFu;
                const bool up = bb > THb;                    // e > 0 ?
                const unsigned int sel = up ? bb : (v >> 16);
                const float f = __uint_as_float(sel << 16);  // bf16 -> f32
                const float as = up ? A : C;
                const unsigned int bit = (eb[i & 3] >> (i >> 2)) & 1u;
                const float p = bit ? f * as : 0.f;
                pb[i] = __builtin_bit_cast(unsigned short, __float2bfloat16(p));
            }

            const bf16x8 af = __builtin_bit_cast(bf16x8, pb);
            #pragma unroll
            for (int qd = 0; qd < 4; ++qd) {
                const uint4 wqv = whts_lds[chl * 256 + qd * 64 + lane];
                const bf16x8 bq = __builtin_bit_cast(bf16x8, wqv);
                acc[qd] = __builtin_amdgcn_mfma_f32_16x16x32_bf16(af, bq, acc[qd], 0, 0, 0);
            }
            accl = __builtin_amdgcn_mfma_f32_16x16x32_bf16(af, bones, accl, 0, 0, 0);
        }
    }

    // write partials (wave owns rows [rb+w*16, +16) of slice jbi exclusively)
    // D layout: col = lane&15 (feature r), row = 4*g + q
    if (r == 0) {
        #pragma unroll
        for (int q = 0; q < 4; ++q)
            pl[(size_t)jbi * NN + rb + w * 16 + 4 * g + q] = accl[q];
    }
    #pragma unroll
    for (int q = 0; q < 4; ++q) {
        const int row = rb + w * 16 + 4 * g + q;
        float* dst = pacc + ((size_t)jbi * NN + row) * OUTF + r;
        dst[0]  = acc[0][q];
        dst[16] = acc[1][q];
        dst[32] = acc[2][q];
        dst[48] = acc[3][q];
    }
}

// ---- Kernel 3: merge j-partials, normalize, ELU
__global__ __launch_bounds__(1024) void merge_kernel(
    const float* __restrict__ pacc, const float* __restrict__ pl,
    float* __restrict__ out)
{
    const size_t idx = (size_t)blockIdx.x * 1024 + threadIdx.x;
    const int row = (int)(idx >> 6);
    float L = 0.f, o = 0.f;
    #pragma unroll
    for (int k = 0; k < 16; ++k) {
        L += pl[(size_t)k * NN + row];
        o += pacc[(size_t)k * NN * OUTF + idx];
    }
    o /= L;
    o = (o > 0.f) ? o : expm1f(o); // ELU
    out[idx] = o;
}

extern "C" void kernel_launch(void* const* d_in, const int* in_sizes, int n_in,
                              void* d_out, int out_size, void* d_ws, size_t ws_size,
                              hipStream_t stream) {
    const float* h = (const float*)d_in[0];
    const int* adj = (const int*)d_in[1];
    const float* W = (const float*)d_in[2];
    const float* a = (const float*)d_in[3];
    float* out = (float*)d_out;

    char* ws = (char*)d_ws;
    unsigned short* WhT = (unsigned short*)ws;                 // 1 MB
    unsigned short* WhTs = (unsigned short*)(ws + (1 << 20));  // 1 MB swizzled
    float* f1 = (float*)(ws + (2 << 20));                      // 32 KB
    float* f2 = f1 + NN;                                       // 32 KB
    float* f2m = f2 + NN;                                      // 4 B (pad 256)
    unsigned int* bd = (unsigned int*)((char*)f2m + 256);      // 32 KB
    float* pacc = (float*)(ws + (4 << 20));                    // 32 MB (16 slices)
    float* pl = (float*)(ws + ((size_t)36 << 20));             // 512 KB

    prep_kernel<<<NN / 32, 256, 0, stream>>>(h, W, a, WhT, f1, f2);
    fmax_kernel<<<1, 1024, 0, stream>>>(f2, f2m);
    bd_kernel<<<NN / 1024, 1024, 0, stream>>>(f2, bd);
    repack_kernel<<<NN / 32, 256, 0, stream>>>(WhT, WhTs);
    gatl_kernel<<<(NN / RB) * (NN / JB), 512, 0, stream>>>(adj, WhTs, f1, bd, f2m, pacc, pl);
    merge_kernel<<<NN * OUTF / 1024, 1024, 0, stream>>>(pacc, pl, out);
}